// Round 1
// baseline (6399.692 us; speedup 1.0000x reference)
//
#include <hip/hip_runtime.h>
#include <math.h>

#define TB 256
#define VOFF 512
#define VBUF (512 + 8192 + 1024)   // 9728 floats: [-512, 8192+1024) zero-padded window

// ---- per-layer sum(bk^2) into ws[0..3] ----
__global__ __launch_bounds__(TB) void y2_kernel(
    const float* __restrict__ bk0, const float* __restrict__ bk1,
    const float* __restrict__ bk2, const float* __restrict__ bk3,
    float* __restrict__ ws)
{
    const float* bks[4] = {bk0, bk1, bk2, bk3};
    const int i = blockIdx.x;
    const int L = 8192 + (i + 1) * 512;
    const float* b = bks[i];
    float s = 0.f;
    for (int n = threadIdx.x; n < L; n += TB) { float x = b[n]; s += x * x; }
    #pragma unroll
    for (int off = 32; off; off >>= 1) s += __shfl_down(s, off, 64);
    __shared__ float sp[4];
    if ((threadIdx.x & 63) == 0) sp[threadIdx.x >> 6] = s;
    __syncthreads();
    if (threadIdx.x == 0) ws[i] = sp[0] + sp[1] + sp[2] + sp[3];
}

// ---- main fused kernel: one block per batch row ----
__global__ __launch_bounds__(TB) void hdcnn_kernel(
    const float* __restrict__ hk, const float* __restrict__ w,
    const float* __restrict__ bk0, const float* __restrict__ bk1,
    const float* __restrict__ bk2, const float* __restrict__ bk3,
    const float* __restrict__ y2w, float* __restrict__ out)
{
    __shared__ float sv[VBUF];
    __shared__ float sw[512];
    __shared__ float sred[8];
    __shared__ float sfin[2];

    const int tid = threadIdx.x;
    const int row = blockIdx.x;

    // zero pads, load v = hk row
    for (int j = tid; j < VOFF; j += TB) sv[j] = 0.f;
    for (int j = VOFF + 8192 + tid; j < VBUF; j += TB) sv[j] = 0.f;
    {
        const float4* src = (const float4*)(hk + (size_t)row * 8192);
        float4* dst = (float4*)(sv + VOFF);
        for (int j = tid; j < 2048; j += TB) dst[j] = src[j];
    }

    const float* bks[4] = {bk0, bk1, bk2, bk3};
    float acc[5][8];

    for (int layer = 0; layer < 4; ++layer) {
        const float* __restrict__ bk = bks[layer];
        for (int j = tid; j < 512; j += TB) sw[j] = w[layer * 512 + j];
        __syncthreads();   // sv (init or prev update) + sw visible to all

        float sum2 = 0.f, sxy = 0.f;

        #pragma unroll
        for (int g = 0; g < 5; ++g) {
            const int n0 = (g * TB + tid) * 8;
            float a0=0.f,a1=0.f,a2=0.f,a3=0.f,a4=0.f,a5=0.f,a6=0.f,a7=0.f;
            if (n0 <= 8702) {   // wave-uniform (group 4: wave 0 only)
                for (int kb = 0; kb < 512; kb += 8) {
                    const float* vb = sv + (VOFF - 8) + n0 - kb;  // 32B aligned
                    float4 v0 = *(const float4*)(vb);
                    float4 v1 = *(const float4*)(vb + 4);
                    float4 v2 = *(const float4*)(vb + 8);
                    float4 v3 = *(const float4*)(vb + 12);
                    float4 w0 = *(const float4*)(sw + kb);
                    float4 w1 = *(const float4*)(sw + kb + 4);
                    float vf[16] = {v0.x,v0.y,v0.z,v0.w, v1.x,v1.y,v1.z,v1.w,
                                    v2.x,v2.y,v2.z,v2.w, v3.x,v3.y,v3.z,v3.w};
                    float wf[8]  = {w0.x,w0.y,w0.z,w0.w, w1.x,w1.y,w1.z,w1.w};
                    #pragma unroll
                    for (int dk = 0; dk < 8; ++dk) {
                        // conv[n0+t] += w[kb+dk] * v[n0+t-kb-dk]
                        a0 += wf[dk] * vf[8 + 0 - dk];
                        a1 += wf[dk] * vf[8 + 1 - dk];
                        a2 += wf[dk] * vf[8 + 2 - dk];
                        a3 += wf[dk] * vf[8 + 3 - dk];
                        a4 += wf[dk] * vf[8 + 4 - dk];
                        a5 += wf[dk] * vf[8 + 5 - dk];
                        a6 += wf[dk] * vf[8 + 6 - dk];
                        a7 += wf[dk] * vf[8 + 7 - dk];
                    }
                }
                float4 b0 = *(const float4*)(bk + n0);
                float4 b1 = *(const float4*)(bk + n0 + 4);
                sum2 += a0*a0+a1*a1+a2*a2+a3*a3+a4*a4+a5*a5+a6*a6+a7*a7;
                sxy  += a0*b0.x+a1*b0.y+a2*b0.z+a3*b0.w
                      + a4*b1.x+a5*b1.y+a6*b1.z+a7*b1.w;
            }
            acc[g][0]=a0; acc[g][1]=a1; acc[g][2]=a2; acc[g][3]=a3;
            acc[g][4]=a4; acc[g][5]=a5; acc[g][6]=a6; acc[g][7]=a7;
        }

        // block reduction of (sum2, sxy)
        #pragma unroll
        for (int off = 32; off; off >>= 1) {
            sum2 += __shfl_down(sum2, off, 64);
            sxy  += __shfl_down(sxy,  off, 64);
        }
        const int wid = tid >> 6;
        if ((tid & 63) == 0) { sred[wid*2] = sum2; sred[wid*2+1] = sxy; }
        __syncthreads();
        if (tid == 0) {
            sfin[0] = sred[0]+sred[2]+sred[4]+sred[6];
            sfin[1] = sred[1]+sred[3]+sred[5]+sred[7];
        }
        __syncthreads();

        // scalars (redundant per thread)
        const float un2 = sfin[0];
        const float xys = sfin[1];
        const float Cc  = 1e-12f;
        const float un  = sqrtf(un2);
        const float unc = fmaxf(un, 1e-15f);
        const float aa  = 1e-6f * unc;            // sqrt(c) * ||u||
        const float f   = tanhf(aa) / aa;         // expmap0 scale
        const float hn  = f * un;                 // ||hyp||
        const float hnc = fmaxf(hn, 1e-15f);
        const float maxn = (1.0f - 0.004f) * 1.0e6f;
        const float s   = (hnc > maxn) ? f * (maxn / hnc) : f;  // proj scale
        const float x2  = s * s * un2;
        const float xy  = s * xys;
        const float y2  = y2w[layer];
        const float t2c = 2.f * Cc * xy;
        const float A   = 1.f + t2c + Cc * y2;
        const float B   = 1.f - Cc * x2;
        float D = 1.f + t2c + Cc * Cc * x2 * y2;
        D = fmaxf(D, 1e-15f);
        const float alpha = A * s / D;
        const float beta  = B / D;

        if (layer < 3) {
            // next v = relu(alpha*conv + beta*bk)[0:8192]  (tail never used)
            #pragma unroll
            for (int g = 0; g < 4; ++g) {
                const int n0 = (g * TB + tid) * 8;
                float4 b0 = *(const float4*)(bk + n0);
                float4 b1 = *(const float4*)(bk + n0 + 4);
                float4 o0, o1;
                o0.x = fmaxf(alpha*acc[g][0] + beta*b0.x, 0.f);
                o0.y = fmaxf(alpha*acc[g][1] + beta*b0.y, 0.f);
                o0.z = fmaxf(alpha*acc[g][2] + beta*b0.z, 0.f);
                o0.w = fmaxf(alpha*acc[g][3] + beta*b0.w, 0.f);
                o1.x = fmaxf(alpha*acc[g][4] + beta*b1.x, 0.f);
                o1.y = fmaxf(alpha*acc[g][5] + beta*b1.y, 0.f);
                o1.z = fmaxf(alpha*acc[g][6] + beta*b1.z, 0.f);
                o1.w = fmaxf(alpha*acc[g][7] + beta*b1.w, 0.f);
                *(float4*)(sv + VOFF + n0)     = o0;
                *(float4*)(sv + VOFF + n0 + 4) = o1;
            }
            // visibility ensured by next layer's __syncthreads
        } else {
            // final output row: 10240 elements (conv==0 for n>=8703 naturally)
            float* orow = out + (size_t)row * 10240;
            #pragma unroll
            for (int g = 0; g < 5; ++g) {
                const int n0 = (g * TB + tid) * 8;
                float4 b0 = *(const float4*)(bk + n0);
                float4 b1 = *(const float4*)(bk + n0 + 4);
                float4 o0, o1;
                o0.x = fmaxf(alpha*acc[g][0] + beta*b0.x, 0.f);
                o0.y = fmaxf(alpha*acc[g][1] + beta*b0.y, 0.f);
                o0.z = fmaxf(alpha*acc[g][2] + beta*b0.z, 0.f);
                o0.w = fmaxf(alpha*acc[g][3] + beta*b0.w, 0.f);
                o1.x = fmaxf(alpha*acc[g][4] + beta*b1.x, 0.f);
                o1.y = fmaxf(alpha*acc[g][5] + beta*b1.y, 0.f);
                o1.z = fmaxf(alpha*acc[g][6] + beta*b1.z, 0.f);
                o1.w = fmaxf(alpha*acc[g][7] + beta*b1.w, 0.f);
                *(float4*)(orow + n0)     = o0;
                *(float4*)(orow + n0 + 4) = o1;
            }
        }
    }
}

extern "C" void kernel_launch(void* const* d_in, const int* in_sizes, int n_in,
                              void* d_out, int out_size, void* d_ws, size_t ws_size,
                              hipStream_t stream) {
    const float* hk  = (const float*)d_in[0];
    const float* w   = (const float*)d_in[1];
    const float* bk0 = (const float*)d_in[2];
    const float* bk1 = (const float*)d_in[3];
    const float* bk2 = (const float*)d_in[4];
    const float* bk3 = (const float*)d_in[5];
    float* out = (float*)d_out;
    float* ws  = (float*)d_ws;

    y2_kernel<<<4, TB, 0, stream>>>(bk0, bk1, bk2, bk3, ws);
    hdcnn_kernel<<<4096, TB, 0, stream>>>(hk, w, bk0, bk1, bk2, bk3, ws, out);
}

// Round 2
// 2252.722 us; speedup vs baseline: 2.8409x; 2.8409x over previous
//
#include <hip/hip_runtime.h>
#include <math.h>

#define TB 512
#define VOFF 520                    // zero pad below v[0]; multiple of 4
#define NV 8704                     // v window extent above VOFF actually used
#define VBUFP 9344                  // ceil((VOFF+NV)/128)*128 physical dwords (swizzle groups of 128 dwords)

// XOR swizzle on dword index: moves d-bits 5..7 into bank bits 2..4.
// Bijective within each 128-dword group; preserves d mod 4 (float4-safe).
__device__ __forceinline__ int swz(int d) { return d ^ ((d >> 3) & 28); }

__device__ __forceinline__ void ld8(float (&dst)[8], const float* sv, int d) {
    int d0 = swz(d);
    int d1 = swz(d + 4);
    *(float4*)(&dst[0]) = *(const float4*)(sv + d0);
    *(float4*)(&dst[4]) = *(const float4*)(sv + d1);
}

__device__ __forceinline__ void st4s(float* sv, int d, float4 v) {
    *(float4*)(sv + swz(d)) = v;
}

// 8 outputs (acc), 8 taps (w8), 16-float window [lo|hi] at base = n0-kb-8:
// acc[t] += w8[dk] * win[8+t-dk]
__device__ __forceinline__ void conv8(float (&acc)[8], const float (&w8)[8],
                                      const float (&lo)[8], const float (&hi)[8]) {
    #pragma unroll
    for (int t = 0; t < 8; ++t) {
        #pragma unroll
        for (int dk = 0; dk < 8; ++dk) {
            const int j = 8 + t - dk;      // 1..15, compile-time
            const float v = (j < 8) ? lo[j] : hi[j - 8];
            acc[t] = fmaf(w8[dk], v, acc[t]);
        }
    }
}

// ---- per-layer sum(bk^2) into ws[0..3] ----
__global__ __launch_bounds__(256) void y2_kernel(
    const float* __restrict__ bk0, const float* __restrict__ bk1,
    const float* __restrict__ bk2, const float* __restrict__ bk3,
    float* __restrict__ ws)
{
    const float* bks[4] = {bk0, bk1, bk2, bk3};
    const int i = blockIdx.x;
    const int L = 8192 + (i + 1) * 512;
    const float* b = bks[i];
    float s = 0.f;
    for (int n = threadIdx.x; n < L; n += 256) { float x = b[n]; s += x * x; }
    #pragma unroll
    for (int off = 32; off; off >>= 1) s += __shfl_down(s, off, 64);
    __shared__ float sp[4];
    if ((threadIdx.x & 63) == 0) sp[threadIdx.x >> 6] = s;
    __syncthreads();
    if (threadIdx.x == 0) ws[i] = sp[0] + sp[1] + sp[2] + sp[3];
}

// ---- main fused kernel: one block per batch row ----
__global__ __launch_bounds__(TB) void hdcnn_kernel(
    const float* __restrict__ hk, const float* __restrict__ w,
    const float* __restrict__ bk0, const float* __restrict__ bk1,
    const float* __restrict__ bk2, const float* __restrict__ bk3,
    const float* __restrict__ y2w, float* __restrict__ out)
{
    __shared__ __align__(16) float sv[VBUFP];
    __shared__ __align__(16) float sw[512];
    __shared__ float sred[16];
    __shared__ float sfin[2];

    const int tid = threadIdx.x;
    const int row = blockIdx.x;
    const bool tail = (tid < 64);      // owns octet at 8192+8*tid

    // zero entire physical buffer (stride-1 scalar stores: conflict-free)
    for (int j = tid; j < VBUFP; j += TB) sv[j] = 0.f;
    __syncthreads();
    // load v = hk row through the swizzle
    {
        const float4* src = (const float4*)(hk + (size_t)row * 8192);
        for (int j = tid; j < 2048; j += TB) st4s(sv, VOFF + 4 * j, src[j]);
    }

    for (int layer = 0; layer < 4; ++layer) {
        const float* __restrict__ bk = (layer == 0) ? bk0 : (layer == 1) ? bk1
                                     : (layer == 2) ? bk2 : bk3;
        if (tid < 128) ((float4*)sw)[tid] = ((const float4*)(w + layer * 512))[tid];
        __syncthreads();   // sv (init or prev layer) + sw visible

        // octets: q=0: n0=8*tid; q=1: n0=4096+8*tid; q=2 (tid<64): n0=8192+8*tid
        float acc[3][8] = {};
        float Wlo[3][8], Whi[3][8];
        #pragma unroll
        for (int q = 0; q < 2; ++q) {
            ld8(Wlo[q], sv, VOFF + 4096 * q + 8 * tid - 8);
            ld8(Whi[q], sv, VOFF + 4096 * q + 8 * tid);
        }
        if (tail) {
            ld8(Wlo[2], sv, VOFF + 8192 + 8 * tid - 8);
            ld8(Whi[2], sv, VOFF + 8192 + 8 * tid);
        }

        // k-loop: 16 taps per iteration, rolling 16-float window, ping-pong
        int t0d = VOFF + 8 * tid - 16;    // = VOFF + 8*tid - kb - 16 at loop top
        for (int kb = 0; kb < 512; kb += 16) {
            float w8a[8], w8b[8];
            *(float4*)(&w8a[0]) = *(const float4*)(sw + kb);
            *(float4*)(&w8a[4]) = *(const float4*)(sw + kb + 4);
            *(float4*)(&w8b[0]) = *(const float4*)(sw + kb + 8);
            *(float4*)(&w8b[4]) = *(const float4*)(sw + kb + 12);
            #pragma unroll
            for (int q = 0; q < 2; ++q) {
                conv8(acc[q], w8a, Wlo[q], Whi[q]);     // taps kb..kb+7
                ld8(Whi[q], sv, t0d + 4096 * q);        // v[n0-kb-16 .. -9]
                conv8(acc[q], w8b, Whi[q], Wlo[q]);     // taps kb+8..kb+15
                ld8(Wlo[q], sv, t0d + 4096 * q - 8);    // v[n0-kb-24 .. -17]
            }
            if (tail) {
                conv8(acc[2], w8a, Wlo[2], Whi[2]);
                ld8(Whi[2], sv, t0d + 8192);
                conv8(acc[2], w8b, Whi[2], Wlo[2]);
                ld8(Wlo[2], sv, t0d + 8192 - 8);
            }
            t0d -= 16;
        }

        // row scalars: sum(conv^2), sum(conv*bk)
        float bq[3][8];
        float sum2 = 0.f, sxy = 0.f;
        #pragma unroll
        for (int q = 0; q < 2; ++q) {
            const int n0 = 4096 * q + 8 * tid;
            *(float4*)(&bq[q][0]) = *(const float4*)(bk + n0);
            *(float4*)(&bq[q][4]) = *(const float4*)(bk + n0 + 4);
            #pragma unroll
            for (int t = 0; t < 8; ++t) {
                sum2 = fmaf(acc[q][t], acc[q][t], sum2);
                sxy  = fmaf(acc[q][t], bq[q][t], sxy);
            }
        }
        if (tail) {
            const int n0 = 8192 + 8 * tid;
            *(float4*)(&bq[2][0]) = *(const float4*)(bk + n0);
            *(float4*)(&bq[2][4]) = *(const float4*)(bk + n0 + 4);
            #pragma unroll
            for (int t = 0; t < 8; ++t) {
                sum2 = fmaf(acc[2][t], acc[2][t], sum2);
                sxy  = fmaf(acc[2][t], bq[2][t], sxy);
            }
        }

        #pragma unroll
        for (int off = 32; off; off >>= 1) {
            sum2 += __shfl_down(sum2, off, 64);
            sxy  += __shfl_down(sxy,  off, 64);
        }
        const int wid = tid >> 6;
        if ((tid & 63) == 0) { sred[wid * 2] = sum2; sred[wid * 2 + 1] = sxy; }
        __syncthreads();
        if (tid == 0) {
            float s2 = 0.f, sx = 0.f;
            #pragma unroll
            for (int i = 0; i < 8; ++i) { s2 += sred[i * 2]; sx += sred[i * 2 + 1]; }
            sfin[0] = s2; sfin[1] = sx;
        }
        __syncthreads();

        // hyperbolic scalars (collapse to alpha, beta)
        const float un2 = sfin[0];
        const float xys = sfin[1];
        const float Cc  = 1e-12f;
        const float un  = sqrtf(un2);
        const float unc = fmaxf(un, 1e-15f);
        const float aa  = 1e-6f * unc;            // sqrt(c) * ||u||
        const float f   = tanhf(aa) / aa;         // expmap0 scale
        const float hn  = f * un;
        const float hnc = fmaxf(hn, 1e-15f);
        const float maxn = (1.0f - 0.004f) * 1.0e6f;
        const float s   = (hnc > maxn) ? f * (maxn / hnc) : f;  // proj scale
        const float x2  = s * s * un2;
        const float xy  = s * xys;
        const float y2  = y2w[layer];
        const float t2c = 2.f * Cc * xy;
        const float A   = 1.f + t2c + Cc * y2;
        const float B   = 1.f - Cc * x2;
        float D = 1.f + t2c + Cc * Cc * x2 * y2;
        D = fmaxf(D, 1e-15f);
        const float alpha = A * s / D;
        const float beta  = B / D;

        if (layer < 3) {
            // next v = relu(alpha*conv + beta*bk)[0:8192]; region >=8192 stays zero
            #pragma unroll
            for (int q = 0; q < 2; ++q) {
                const int n0 = 4096 * q + 8 * tid;
                float4 o0, o1;
                o0.x = fmaxf(alpha * acc[q][0] + beta * bq[q][0], 0.f);
                o0.y = fmaxf(alpha * acc[q][1] + beta * bq[q][1], 0.f);
                o0.z = fmaxf(alpha * acc[q][2] + beta * bq[q][2], 0.f);
                o0.w = fmaxf(alpha * acc[q][3] + beta * bq[q][3], 0.f);
                o1.x = fmaxf(alpha * acc[q][4] + beta * bq[q][4], 0.f);
                o1.y = fmaxf(alpha * acc[q][5] + beta * bq[q][5], 0.f);
                o1.z = fmaxf(alpha * acc[q][6] + beta * bq[q][6], 0.f);
                o1.w = fmaxf(alpha * acc[q][7] + beta * bq[q][7], 0.f);
                st4s(sv, VOFF + n0,     o0);
                st4s(sv, VOFF + n0 + 4, o1);
            }
            // barrier at top of next layer orders these writes before reads
        } else {
            float* orow = out + (size_t)row * 10240;
            #pragma unroll
            for (int q = 0; q < 2; ++q) {
                const int n0 = 4096 * q + 8 * tid;
                float4 o0, o1;
                o0.x = fmaxf(alpha * acc[q][0] + beta * bq[q][0], 0.f);
                o0.y = fmaxf(alpha * acc[q][1] + beta * bq[q][1], 0.f);
                o0.z = fmaxf(alpha * acc[q][2] + beta * bq[q][2], 0.f);
                o0.w = fmaxf(alpha * acc[q][3] + beta * bq[q][3], 0.f);
                o1.x = fmaxf(alpha * acc[q][4] + beta * bq[q][4], 0.f);
                o1.y = fmaxf(alpha * acc[q][5] + beta * bq[q][5], 0.f);
                o1.z = fmaxf(alpha * acc[q][6] + beta * bq[q][6], 0.f);
                o1.w = fmaxf(alpha * acc[q][7] + beta * bq[q][7], 0.f);
                *(float4*)(orow + n0)     = o0;
                *(float4*)(orow + n0 + 4) = o1;
            }
            if (tail) {
                const int n0 = 8192 + 8 * tid;    // conv defined through 8702; conv[8703]=0 naturally
                float4 o0, o1;
                o0.x = fmaxf(alpha * acc[2][0] + beta * bq[2][0], 0.f);
                o0.y = fmaxf(alpha * acc[2][1] + beta * bq[2][1], 0.f);
                o0.z = fmaxf(alpha * acc[2][2] + beta * bq[2][2], 0.f);
                o0.w = fmaxf(alpha * acc[2][3] + beta * bq[2][3], 0.f);
                o1.x = fmaxf(alpha * acc[2][4] + beta * bq[2][4], 0.f);
                o1.y = fmaxf(alpha * acc[2][5] + beta * bq[2][5], 0.f);
                o1.z = fmaxf(alpha * acc[2][6] + beta * bq[2][6], 0.f);
                o1.w = fmaxf(alpha * acc[2][7] + beta * bq[2][7], 0.f);
                *(float4*)(orow + n0)     = o0;
                *(float4*)(orow + n0 + 4) = o1;
            }
            if (tid < 384) {                      // pure-bias region 8704..10239
                const int n = 8704 + 4 * tid;
                float4 b4 = *(const float4*)(bk + n);
                float4 o;
                o.x = fmaxf(beta * b4.x, 0.f);
                o.y = fmaxf(beta * b4.y, 0.f);
                o.z = fmaxf(beta * b4.z, 0.f);
                o.w = fmaxf(beta * b4.w, 0.f);
                *(float4*)(orow + n) = o;
            }
        }
    }
}

extern "C" void kernel_launch(void* const* d_in, const int* in_sizes, int n_in,
                              void* d_out, int out_size, void* d_ws, size_t ws_size,
                              hipStream_t stream) {
    const float* hk  = (const float*)d_in[0];
    const float* w   = (const float*)d_in[1];
    const float* bk0 = (const float*)d_in[2];
    const float* bk1 = (const float*)d_in[3];
    const float* bk2 = (const float*)d_in[4];
    const float* bk3 = (const float*)d_in[5];
    float* out = (float*)d_out;
    float* ws  = (float*)d_ws;

    y2_kernel<<<4, 256, 0, stream>>>(bk0, bk1, bk2, bk3, ws);
    hdcnn_kernel<<<4096, TB, 0, stream>>>(hk, w, bk0, bk1, bk2, bk3, ws, out);
}

// Round 3
// 1152.391 us; speedup vs baseline: 5.5534x; 1.9548x over previous
//
#include <hip/hip_runtime.h>
#include <hip/hip_bf16.h>
#include <math.h>

#define TB 768
#define NW 12                 // waves per block
#define VOFFH 512             // halves of zero pad below v[0]
#define SVH 9760              // bf16 halves in sv (covers inactive-tile reads)

typedef __attribute__((ext_vector_type(8))) short bf16x8;
typedef __attribute__((ext_vector_type(4))) float f32x4;

__device__ __forceinline__ short f2b(float x) {
    union { __hip_bfloat16 h; short s; } u;
    u.h = __float2bfloat16(x);
    return u.s;
}

// ---- per-layer sum(bk^2) into ws[0..3] ----
__global__ __launch_bounds__(256) void y2_kernel(
    const float* __restrict__ bk0, const float* __restrict__ bk1,
    const float* __restrict__ bk2, const float* __restrict__ bk3,
    float* __restrict__ ws)
{
    const float* bks[4] = {bk0, bk1, bk2, bk3};
    const int i = blockIdx.x;
    const int L = 8192 + (i + 1) * 512;
    const float* b = bks[i];
    float s = 0.f;
    for (int n = threadIdx.x; n < L; n += 256) { float x = b[n]; s += x * x; }
    #pragma unroll
    for (int off = 32; off; off >>= 1) s += __shfl_down(s, off, 64);
    __shared__ float sp[4];
    if ((threadIdx.x & 63) == 0) sp[threadIdx.x >> 6] = s;
    __syncthreads();
    if (threadIdx.x == 0) ws[i] = sp[0] + sp[1] + sp[2] + sp[3];
}

// ---- main fused kernel: one block per batch row, MFMA Toeplitz conv ----
__global__ __launch_bounds__(TB) void hdcnn_kernel(
    const float* __restrict__ hk, const float* __restrict__ w,
    const float* __restrict__ bk0, const float* __restrict__ bk1,
    const float* __restrict__ bk2, const float* __restrict__ bk3,
    const float* __restrict__ y2w, float* __restrict__ out)
{
    __shared__ __align__(16) short svb[SVH];   // bf16 image of v, zero-padded
    __shared__ float sred[NW * 2];

    const int tid  = threadIdx.x;
    const int row  = blockIdx.x;
    const int lane = tid & 63;
    const int wv   = tid >> 6;
    const int jn   = lane & 15;   // MFMA col (j) / A row (r) selector
    const int kq   = lane >> 4;   // k-quadrant

    // zero-fill sv (covers all pad + inactive-tile read range)
    {
        int* svi = (int*)svb;
        for (int i = tid; i < SVH / 2; i += TB) svi[i] = 0;
    }
    __syncthreads();

    // layer-0 input: hk row -> bf16 at VOFFH
    {
        const float4* hrow = (const float4*)(hk + (size_t)row * 8192);
        for (int j = tid; j < 1024; j += TB) {
            float4 x0 = hrow[2 * j];
            float4 x1 = hrow[2 * j + 1];
            bf16x8 p;
            p[0] = f2b(x0.x); p[1] = f2b(x0.y); p[2] = f2b(x0.z); p[3] = f2b(x0.w);
            p[4] = f2b(x1.x); p[5] = f2b(x1.y); p[6] = f2b(x1.z); p[7] = f2b(x1.w);
            *(bf16x8*)(svb + VOFFH + 8 * j) = p;
        }
    }

    // wave's three tiles (t2 may be inactive; its sv region is all-zero -> acc2=0)
    const int t0 = wv, t1 = wv + NW, t2 = wv + 2 * NW;
    const bool act2 = (t2 < 34);
    const int hb0 = t0 * 256 + jn * 16 + kq * 8;
    const int hb1 = t1 * 256 + jn * 16 + kq * 8;
    const int hb2 = t2 * 256 + jn * 16 + kq * 8;
    const int nb0 = t0 * 256 + kq * 64 + jn;
    const int nb1 = t1 * 256 + kq * 64 + jn;
    const int nb2 = t2 * 256 + kq * 64 + jn;

    for (int layer = 0; layer < 4; ++layer) {
        const float* __restrict__ bk = (layer == 0) ? bk0 : (layer == 1) ? bk1
                                     : (layer == 2) ? bk2 : bk3;
        const float* __restrict__ wl = w + layer * 512;

        // B fragments in registers: B[m,j] = w[512 + j - m], m = ks*32 + kq*8 + jj
        bf16x8 Bf[17];
        #pragma unroll
        for (int ks = 0; ks < 17; ++ks) {
            bf16x8 bb;
            #pragma unroll
            for (int jj = 0; jj < 8; ++jj) {
                const int m = ks * 32 + kq * 8 + jj;
                const int idx = 512 + jn - m;
                const float val = (idx >= 0 && idx < 512) ? wl[idx] : 0.f;
                bb[jj] = f2b(val);
            }
            Bf[ks] = bb;
        }

        __syncthreads();   // prev-layer v writes (or initial load) visible

        // bias values for this wave's output slots (prefetch before k-loop)
        f32x4 bq0, bq1, bq2;
        #pragma unroll
        for (int i = 0; i < 4; ++i) {
            bq0[i] = bk[nb0 + 16 * i];
            bq1[i] = bk[nb1 + 16 * i];
            bq2[i] = act2 ? bk[nb2 + 16 * i] : 0.f;
        }

        // phase 1: Toeplitz GEMM, 3 interleaved tiles
        f32x4 acc0 = {0.f, 0.f, 0.f, 0.f};
        f32x4 acc1 = {0.f, 0.f, 0.f, 0.f};
        f32x4 acc2 = {0.f, 0.f, 0.f, 0.f};
        #pragma unroll
        for (int ks = 0; ks < 17; ++ks) {
            bf16x8 a0 = *(const bf16x8*)(svb + hb0 + ks * 32);
            bf16x8 a1 = *(const bf16x8*)(svb + hb1 + ks * 32);
            bf16x8 a2 = *(const bf16x8*)(svb + hb2 + ks * 32);
            acc0 = __builtin_amdgcn_mfma_f32_16x16x32_bf16(a0, Bf[ks], acc0, 0, 0, 0);
            acc1 = __builtin_amdgcn_mfma_f32_16x16x32_bf16(a1, Bf[ks], acc1, 0, 0, 0);
            acc2 = __builtin_amdgcn_mfma_f32_16x16x32_bf16(a2, Bf[ks], acc2, 0, 0, 0);
        }

        // row scalars: sum(conv^2), sum(conv*bk)   (acc2==0 when inactive)
        float sum2 = 0.f, sxy = 0.f;
        #pragma unroll
        for (int i = 0; i < 4; ++i) {
            sum2 = fmaf(acc0[i], acc0[i], sum2);
            sum2 = fmaf(acc1[i], acc1[i], sum2);
            sum2 = fmaf(acc2[i], acc2[i], sum2);
            sxy  = fmaf(acc0[i], bq0[i], sxy);
            sxy  = fmaf(acc1[i], bq1[i], sxy);
            sxy  = fmaf(acc2[i], bq2[i], sxy);
        }
        #pragma unroll
        for (int off = 32; off; off >>= 1) {
            sum2 += __shfl_down(sum2, off, 64);
            sxy  += __shfl_down(sxy,  off, 64);
        }
        if (lane == 0) { sred[wv * 2] = sum2; sred[wv * 2 + 1] = sxy; }
        __syncthreads();
        float un2 = 0.f, xys = 0.f;
        #pragma unroll
        for (int i = 0; i < NW; ++i) { un2 += sred[2 * i]; xys += sred[2 * i + 1]; }

        // hyperbolic scalars -> alpha, beta
        const float Cc  = 1e-12f;
        const float un  = sqrtf(un2);
        const float unc = fmaxf(un, 1e-15f);
        const float aa  = 1e-6f * unc;            // sqrt(c) * ||u||
        const float f   = tanhf(aa) / aa;         // expmap0 scale
        const float hn  = f * un;
        const float hnc = fmaxf(hn, 1e-15f);
        const float maxn = (1.0f - 0.004f) * 1.0e6f;
        const float s   = (hnc > maxn) ? f * (maxn / hnc) : f;  // proj scale
        const float x2  = s * s * un2;
        const float xy  = s * xys;
        const float y2  = y2w[layer];
        const float t2c = 2.f * Cc * xy;
        const float A   = 1.f + t2c + Cc * y2;
        const float B   = 1.f - Cc * x2;
        float D = 1.f + t2c + Cc * Cc * x2 * y2;
        D = fmaxf(D, 1e-15f);
        const float alpha = A * s / D;
        const float beta  = B / D;

        // phase 3: produce next v (LDS bf16) or final output
        if (layer < 3) {
            // only n < 8192 feeds the next layer (tiles 32,33 stay zero)
            if (t0 < 32) {
                #pragma unroll
                for (int i = 0; i < 4; ++i)
                    svb[VOFFH + nb0 + 16 * i] =
                        f2b(fmaxf(alpha * acc0[i] + beta * bq0[i], 0.f));
            }
            if (t1 < 32) {
                #pragma unroll
                for (int i = 0; i < 4; ++i)
                    svb[VOFFH + nb1 + 16 * i] =
                        f2b(fmaxf(alpha * acc1[i] + beta * bq1[i], 0.f));
            }
            if (t2 < 32) {
                #pragma unroll
                for (int i = 0; i < 4; ++i)
                    svb[VOFFH + nb2 + 16 * i] =
                        f2b(fmaxf(alpha * acc2[i] + beta * bq2[i], 0.f));
            }
        } else {
            float* orow = out + (size_t)row * 10240;
            #pragma unroll
            for (int i = 0; i < 4; ++i) {
                orow[nb0 + 16 * i] = fmaxf(alpha * acc0[i] + beta * bq0[i], 0.f);
                orow[nb1 + 16 * i] = fmaxf(alpha * acc1[i] + beta * bq1[i], 0.f);
            }
            if (act2) {
                #pragma unroll
                for (int i = 0; i < 4; ++i)
                    orow[nb2 + 16 * i] = fmaxf(alpha * acc2[i] + beta * bq2[i], 0.f);
            }
            for (int n = 8704 + tid; n < 10240; n += TB)
                orow[n] = fmaxf(beta * bk[n], 0.f);
        }
    }
}

extern "C" void kernel_launch(void* const* d_in, const int* in_sizes, int n_in,
                              void* d_out, int out_size, void* d_ws, size_t ws_size,
                              hipStream_t stream) {
    const float* hk  = (const float*)d_in[0];
    const float* w   = (const float*)d_in[1];
    const float* bk0 = (const float*)d_in[2];
    const float* bk1 = (const float*)d_in[3];
    const float* bk2 = (const float*)d_in[4];
    const float* bk3 = (const float*)d_in[5];
    float* out = (float*)d_out;
    float* ws  = (float*)d_ws;

    y2_kernel<<<4, 256, 0, stream>>>(bk0, bk1, bk2, bk3, ws);
    hdcnn_kernel<<<4096, TB, 0, stream>>>(hk, w, bk0, bk1, bk2, bk3, ws, out);
}

// Round 4
// 312.176 us; speedup vs baseline: 20.5002x; 3.6915x over previous
//
#include <hip/hip_runtime.h>
#include <hip/hip_bf16.h>
#include <math.h>

#define TB 768
#define NW 12                 // waves per block
#define VOFFH 512             // halves of zero pad below v[0]
#define SVH 9760              // bf16 halves in sv (covers inactive-tile reads)
#define NFRAG 1088            // 17 ks-steps * 64 lanes

typedef __attribute__((ext_vector_type(8))) short bf16x8;
typedef __attribute__((ext_vector_type(4))) float f32x4;

__device__ __forceinline__ short f2b(float x) {
    union { __hip_bfloat16 h; short s; } u;
    u.h = __float2bfloat16(x);
    return u.s;
}

// ---- per-layer sum(bk^2) into ws[0..3] ----
__global__ __launch_bounds__(256) void y2_kernel(
    const float* __restrict__ bk0, const float* __restrict__ bk1,
    const float* __restrict__ bk2, const float* __restrict__ bk3,
    float* __restrict__ ws)
{
    const float* bks[4] = {bk0, bk1, bk2, bk3};
    const int i = blockIdx.x;
    const int L = 8192 + (i + 1) * 512;
    const float* b = bks[i];
    float s = 0.f;
    for (int n = threadIdx.x; n < L; n += 256) { float x = b[n]; s += x * x; }
    #pragma unroll
    for (int off = 32; off; off >>= 1) s += __shfl_down(s, off, 64);
    __shared__ float sp[4];
    if ((threadIdx.x & 63) == 0) sp[threadIdx.x >> 6] = s;
    __syncthreads();
    if (threadIdx.x == 0) ws[i] = sp[0] + sp[1] + sp[2] + sp[3];
}

// ---- main fused kernel: one block per batch row, transposed-Toeplitz MFMA ----
__global__ __launch_bounds__(TB) void hdcnn_kernel(
    const float* __restrict__ hk, const float* __restrict__ w,
    const float* __restrict__ bk0, const float* __restrict__ bk1,
    const float* __restrict__ bk2, const float* __restrict__ bk3,
    const float* __restrict__ y2w, float* __restrict__ out)
{
    __shared__ __align__(16) short svb[SVH];        // bf16 image of v, zero-padded
    __shared__ __align__(16) float swl[512];        // staged w row
    __shared__ __align__(16) short swf[NFRAG * 8];  // per-lane A (Toeplitz-w) fragments
    __shared__ float sred[NW * 2];

    const int tid  = threadIdx.x;
    const int row  = blockIdx.x;
    const int lane = tid & 63;
    const int wv   = tid >> 6;
    const int jn   = lane & 15;   // D col selector
    const int kq   = lane >> 4;   // k-quadrant / D row group

    // zero-fill sv (pad + inactive-tile read range)
    {
        int* svi = (int*)svb;
        for (int i = tid; i < SVH / 2; i += TB) svi[i] = 0;
    }
    __syncthreads();

    // layer-0 input: hk row -> bf16 at VOFFH
    {
        const float4* hrow = (const float4*)(hk + (size_t)row * 8192);
        for (int j = tid; j < 1024; j += TB) {
            float4 x0 = hrow[2 * j];
            float4 x1 = hrow[2 * j + 1];
            bf16x8 p;
            p[0] = f2b(x0.x); p[1] = f2b(x0.y); p[2] = f2b(x0.z); p[3] = f2b(x0.w);
            p[4] = f2b(x1.x); p[5] = f2b(x1.y); p[6] = f2b(x1.z); p[7] = f2b(x1.w);
            *(bf16x8*)(svb + VOFFH + 8 * j) = p;
        }
    }

    // wave's three tiles (t2 may be inactive; its sv region is all-zero -> acc2=0)
    const int t0 = wv, t1 = wv + NW, t2 = wv + 2 * NW;
    const bool act2 = (t2 < 34);
    // v-operand (B) read base, halves: VOFFH + t*256 + 16*jn + kq*8 - 512
    const int vb0 = t0 * 256 + 16 * jn + kq * 8;
    const int vb1 = t1 * 256 + 16 * jn + kq * 8;
    const int vb2 = t2 * 256 + 16 * jn + kq * 8;
    // output/bias base: n = t*256 + 16*jn + 4*kq + i  (i=0..3 contiguous)
    const int nb0 = t0 * 256 + 16 * jn + 4 * kq;
    const int nb1 = t1 * 256 + 16 * jn + 4 * kq;
    const int nb2 = t2 * 256 + 16 * jn + 4 * kq;

    for (int layer = 0; layer < 4; ++layer) {
        const float* __restrict__ bk = (layer == 0) ? bk0 : (layer == 1) ? bk1
                                     : (layer == 2) ? bk2 : bk3;

        // stage this layer's w (coalesced)
        if (tid < 128) ((float4*)swl)[tid] = ((const float4*)(w + layer * 512))[tid];
        __syncthreads();   // swl ready; prev writeback visible; prev swf reads done

        // build per-lane A fragments: A[r, m] = w[512 + r - m]
        for (int f = tid; f < NFRAG; f += TB) {
            const int ks = f >> 6;
            const int ln = f & 63;
            const int r  = ln & 15;
            const int kb = ks * 32 + (ln >> 4) * 8;
            bf16x8 bb;
            #pragma unroll
            for (int jj = 0; jj < 8; ++jj) {
                const int idx = 512 + r - (kb + jj);
                const float val = (idx >= 0 && idx < 512) ? swl[idx] : 0.f;
                bb[jj] = f2b(val);
            }
            *(bf16x8*)(swf + f * 8) = bb;
        }

        // bias prefetch (coalesced float4 per lane)
        f32x4 bq0, bq1, bq2;
        {
            float4 a = *(const float4*)(bk + nb0);
            float4 b = *(const float4*)(bk + nb1);
            bq0[0] = a.x; bq0[1] = a.y; bq0[2] = a.z; bq0[3] = a.w;
            bq1[0] = b.x; bq1[1] = b.y; bq1[2] = b.z; bq1[3] = b.w;
            if (act2) {
                float4 c = *(const float4*)(bk + nb2);
                bq2[0] = c.x; bq2[1] = c.y; bq2[2] = c.z; bq2[3] = c.w;
            } else {
                bq2[0] = 0.f; bq2[1] = 0.f; bq2[2] = 0.f; bq2[3] = 0.f;
            }
        }
        __syncthreads();   // swf ready

        // Toeplitz GEMM: D = W_toep(A) x V_windows(B), 3 interleaved tiles
        f32x4 acc0 = {0.f, 0.f, 0.f, 0.f};
        f32x4 acc1 = {0.f, 0.f, 0.f, 0.f};
        f32x4 acc2 = {0.f, 0.f, 0.f, 0.f};
        #pragma unroll
        for (int ks = 0; ks < 17; ++ks) {
            bf16x8 af = *(const bf16x8*)(swf + (ks * 64 + lane) * 8);
            bf16x8 v0 = *(const bf16x8*)(svb + vb0 + ks * 32);
            bf16x8 v1 = *(const bf16x8*)(svb + vb1 + ks * 32);
            bf16x8 v2 = *(const bf16x8*)(svb + vb2 + ks * 32);
            acc0 = __builtin_amdgcn_mfma_f32_16x16x32_bf16(af, v0, acc0, 0, 0, 0);
            acc1 = __builtin_amdgcn_mfma_f32_16x16x32_bf16(af, v1, acc1, 0, 0, 0);
            acc2 = __builtin_amdgcn_mfma_f32_16x16x32_bf16(af, v2, acc2, 0, 0, 0);
        }

        // row scalars: sum(conv^2), sum(conv*bk)
        float sum2 = 0.f, sxy = 0.f;
        #pragma unroll
        for (int i = 0; i < 4; ++i) {
            sum2 = fmaf(acc0[i], acc0[i], sum2);
            sum2 = fmaf(acc1[i], acc1[i], sum2);
            sum2 = fmaf(acc2[i], acc2[i], sum2);
            sxy  = fmaf(acc0[i], bq0[i], sxy);
            sxy  = fmaf(acc1[i], bq1[i], sxy);
            sxy  = fmaf(acc2[i], bq2[i], sxy);
        }
        #pragma unroll
        for (int off = 32; off; off >>= 1) {
            sum2 += __shfl_down(sum2, off, 64);
            sxy  += __shfl_down(sxy,  off, 64);
        }
        if (lane == 0) { sred[wv * 2] = sum2; sred[wv * 2 + 1] = sxy; }
        __syncthreads();
        float un2 = 0.f, xys = 0.f;
        #pragma unroll
        for (int i = 0; i < NW; ++i) { un2 += sred[2 * i]; xys += sred[2 * i + 1]; }

        // hyperbolic scalars -> alpha, beta
        const float Cc  = 1e-12f;
        const float un  = sqrtf(un2);
        const float unc = fmaxf(un, 1e-15f);
        const float aa  = 1e-6f * unc;            // sqrt(c) * ||u||
        const float f   = tanhf(aa) / aa;         // expmap0 scale
        const float hn  = f * un;
        const float hnc = fmaxf(hn, 1e-15f);
        const float maxn = (1.0f - 0.004f) * 1.0e6f;
        const float s   = (hnc > maxn) ? f * (maxn / hnc) : f;  // proj scale
        const float x2  = s * s * un2;
        const float xy  = s * xys;
        const float y2  = y2w[layer];
        const float t2c = 2.f * Cc * xy;
        const float A   = 1.f + t2c + Cc * y2;
        const float B   = 1.f - Cc * x2;
        float D = 1.f + t2c + Cc * Cc * x2 * y2;
        D = fmaxf(D, 1e-15f);
        const float alpha = A * s / D;
        const float beta  = B / D;

        if (layer < 3) {
            // next v = relu(alpha*conv + beta*bk)[0:8192] as bf16 (short4 per lane)
            if (t0 < 32) {
                short4 o;
                o.x = f2b(fmaxf(alpha * acc0[0] + beta * bq0[0], 0.f));
                o.y = f2b(fmaxf(alpha * acc0[1] + beta * bq0[1], 0.f));
                o.z = f2b(fmaxf(alpha * acc0[2] + beta * bq0[2], 0.f));
                o.w = f2b(fmaxf(alpha * acc0[3] + beta * bq0[3], 0.f));
                *(short4*)(svb + VOFFH + nb0) = o;
            }
            if (t1 < 32) {
                short4 o;
                o.x = f2b(fmaxf(alpha * acc1[0] + beta * bq1[0], 0.f));
                o.y = f2b(fmaxf(alpha * acc1[1] + beta * bq1[1], 0.f));
                o.z = f2b(fmaxf(alpha * acc1[2] + beta * bq1[2], 0.f));
                o.w = f2b(fmaxf(alpha * acc1[3] + beta * bq1[3], 0.f));
                *(short4*)(svb + VOFFH + nb1) = o;
            }
            if (t2 < 32) {
                short4 o;
                o.x = f2b(fmaxf(alpha * acc2[0] + beta * bq2[0], 0.f));
                o.y = f2b(fmaxf(alpha * acc2[1] + beta * bq2[1], 0.f));
                o.z = f2b(fmaxf(alpha * acc2[2] + beta * bq2[2], 0.f));
                o.w = f2b(fmaxf(alpha * acc2[3] + beta * bq2[3], 0.f));
                *(short4*)(svb + VOFFH + nb2) = o;
            }
        } else {
            float* orow = out + (size_t)row * 10240;
            float4 o;
            o.x = fmaxf(alpha * acc0[0] + beta * bq0[0], 0.f);
            o.y = fmaxf(alpha * acc0[1] + beta * bq0[1], 0.f);
            o.z = fmaxf(alpha * acc0[2] + beta * bq0[2], 0.f);
            o.w = fmaxf(alpha * acc0[3] + beta * bq0[3], 0.f);
            *(float4*)(orow + nb0) = o;
            o.x = fmaxf(alpha * acc1[0] + beta * bq1[0], 0.f);
            o.y = fmaxf(alpha * acc1[1] + beta * bq1[1], 0.f);
            o.z = fmaxf(alpha * acc1[2] + beta * bq1[2], 0.f);
            o.w = fmaxf(alpha * acc1[3] + beta * bq1[3], 0.f);
            *(float4*)(orow + nb1) = o;
            if (act2) {
                o.x = fmaxf(alpha * acc2[0] + beta * bq2[0], 0.f);
                o.y = fmaxf(alpha * acc2[1] + beta * bq2[1], 0.f);
                o.z = fmaxf(alpha * acc2[2] + beta * bq2[2], 0.f);
                o.w = fmaxf(alpha * acc2[3] + beta * bq2[3], 0.f);
                *(float4*)(orow + nb2) = o;
            }
            if (tid < 384) {                      // pure-bias region 8704..10239
                const int n = 8704 + 4 * tid;
                float4 b4 = *(const float4*)(bk + n);
                float4 ot;
                ot.x = fmaxf(beta * b4.x, 0.f);
                ot.y = fmaxf(beta * b4.y, 0.f);
                ot.z = fmaxf(beta * b4.z, 0.f);
                ot.w = fmaxf(beta * b4.w, 0.f);
                *(float4*)(orow + n) = ot;
            }
        }
    }
}

extern "C" void kernel_launch(void* const* d_in, const int* in_sizes, int n_in,
                              void* d_out, int out_size, void* d_ws, size_t ws_size,
                              hipStream_t stream) {
    const float* hk  = (const float*)d_in[0];
    const float* w   = (const float*)d_in[1];
    const float* bk0 = (const float*)d_in[2];
    const float* bk1 = (const float*)d_in[3];
    const float* bk2 = (const float*)d_in[4];
    const float* bk3 = (const float*)d_in[5];
    float* out = (float*)d_out;
    float* ws  = (float*)d_ws;

    y2_kernel<<<4, 256, 0, stream>>>(bk0, bk1, bk2, bk3, ws);
    hdcnn_kernel<<<4096, TB, 0, stream>>>(hk, w, bk0, bk1, bk2, bk3, ws, out);
}